// Round 13
// baseline (38.280 us; speedup 1.0000x reference)
//
#include <hip/hip_runtime.h>

#define H 32
#define C 64
#define K 15
#define SIGMA 0.3f
#define WAVES 2          // waves per block (block = 128)
#define QPW 4            // queries per wave

// ---- tiny pack kernel: s_pts (N,3) -> ws float4 (N,4), 16B-aligned rows ----
__global__ __launch_bounds__(256) void pack_pts(
    const float* __restrict__ s_pts, float4* __restrict__ sp4, int N)
{
    const int i = blockIdx.x * 256 + threadIdx.x;
    if (i < N)
        sp4[i] = make_float4(s_pts[i * 3 + 0], s_pts[i * 3 + 1], s_pts[i * 3 + 2], 0.0f);
}

template <bool PACKED>
__global__ __launch_bounds__(128) void kpconv_kernel(
    const float*  __restrict__ q_pts,
    const float*  __restrict__ s_pts,
    const float4* __restrict__ sp4,
    const float*  __restrict__ s_feats,
    const int*    __restrict__ inds,
    const float*  __restrict__ weights,
    const float*  __restrict__ kpts,
    float*        __restrict__ out,
    int N)
{
    // padded row (34 float2 = 272 B): q-rows stay 16B-aligned
    __shared__ float2 list[WAVES][QPW][34];   // ~2.2 KB

    const int tid  = threadIdx.x;
    const int wave = tid >> 6;
    const int lane = tid & 63;
    const int half = lane >> 5;          // query within the pass
    const int hl   = lane & 31;          // neighbor slot

    // wave-uniform kernel points -> SGPRs via s_load
    float kp[K * 3];
    #pragma unroll
    for (int i = 0; i < K * 3; ++i) kp[i] = kpts[i];

    const int qBase = (blockIdx.x * WAVES + wave) * QPW;

    int c0 = 0, c1 = 0, c2 = 0, c3 = 0;  // active counts, wave-uniform

    // ---- Phase A: two passes, each pass = 2 queries x 32 neighbors ----
    #pragma unroll
    for (int p = 0; p < 2; ++p) {
        const int m = qBase + p * 2 + half;
        float infl = 0.0f;
        int   packed = 0;
        if (m < N) {
            const int idx = inds[m * H + hl];    // coalesced
            if (idx >= 0 && idx < N) {
                const float qx = q_pts[m * 3 + 0];
                const float qy = q_pts[m * 3 + 1];
                const float qz = q_pts[m * 3 + 2];
                float sx, sy, sz;
                if (PACKED) {
                    const float4 s = sp4[idx];   // ONE dwordx4 line-request
                    sx = s.x; sy = s.y; sz = s.z;
                } else {
                    sx = s_pts[idx * 3 + 0];
                    sy = s_pts[idx * 3 + 1];
                    sz = s_pts[idx * 3 + 2];
                }
                const float nx = sx - qx;
                const float ny = sy - qy;
                const float nz = sz - qz;
                float best = 1e30f;
                int   kbest = 0;
                #pragma unroll
                for (int k = 0; k < K; ++k) {    // math bit-identical to R6/R11
                    const float dx = nx - kp[k * 3 + 0];
                    const float dy = ny - kp[k * 3 + 1];
                    const float dz = nz - kp[k * 3 + 2];
                    const float d2 = dx * dx + dy * dy + dz * dz;
                    if (d2 < best) { best = d2; kbest = k; }
                }
                infl = 1.0f - __builtin_amdgcn_sqrtf(best) * (1.0f / SIGMA);
                if (infl < 0.0f) infl = 0.0f;
                packed = idx | (kbest << 20);
            }
        }
        const unsigned long long ball = __ballot(infl > 0.0f);
        const unsigned int lo = (unsigned int)(ball & 0xFFFFFFFFu);
        const unsigned int hi = (unsigned int)(ball >> 32);
        const unsigned int maskH = half ? hi : lo;
        const int rank = __popc(maskH & ((1u << hl) - 1u));
        if (infl > 0.0f)
            list[wave][p * 2 + half][rank] = make_float2(__int_as_float(packed), infl);
        if (p == 0) { c0 = __popc(lo); c1 = __popc(hi); }
        else        { c2 = __popc(lo); c3 = __popc(hi); }
    }
    // same-wave LDS RAW: DS pipe is in-order per wave; no barrier needed.

    // ---- Phase B: quarter-wave per query, float4 channels, 2 pops/iter ----
    const int q  = lane >> 4;            // which of the 4 queries
    const int ql = lane & 15;            // channel group (4 channels)
    const int cq = (q < 2) ? (q == 0 ? c0 : c1) : (q == 2 ? c2 : c3);
    int maxc = c0 > c1 ? c0 : c1;
    if (c2 > maxc) maxc = c2;
    if (c3 > maxc) maxc = c3;

    float4 acc = make_float4(0.0f, 0.0f, 0.0f, 0.0f);
    for (int i = 0; i < maxc; i += 2) {
        if (i < cq) {
            const float4 pf = *(const float4*)&list[wave][q][i];  // 16B aligned
            const int   p0   = __float_as_int(pf.x);
            const float f0   = pf.y;
            const bool  has1 = (i + 1) < cq;
            const int   p1   = has1 ? __float_as_int(pf.z) : 0;   // row 0: hot line
            const float f1   = has1 ? pf.w : 0.0f;
            const float4 a0 = *(const float4*)(s_feats + (size_t)(p0 & 0xFFFFF) * C + ql * 4);
            const float4 w0 = *(const float4*)(weights + (p0 >> 20) * C + ql * 4);
            const float4 a1 = *(const float4*)(s_feats + (size_t)(p1 & 0xFFFFF) * C + ql * 4);
            const float4 w1 = *(const float4*)(weights + (p1 >> 20) * C + ql * 4);
            acc.x += a0.x * w0.x * f0;  acc.y += a0.y * w0.y * f0;
            acc.z += a0.z * w0.z * f0;  acc.w += a0.w * w0.w * f0;
            acc.x += a1.x * w1.x * f1;  acc.y += a1.y * w1.y * f1;
            acc.z += a1.z * w1.z * f1;  acc.w += a1.w * w1.w * f1;
        }
    }

    const int mq = qBase + q;
    if (mq < N)
        *(float4*)(out + (size_t)mq * C + ql * 4) = acc;   // 256B per query
}

extern "C" void kernel_launch(void* const* d_in, const int* in_sizes, int n_in,
                              void* d_out, int out_size, void* d_ws, size_t ws_size,
                              hipStream_t stream) {
    const float* q_pts   = (const float*)d_in[0];
    const float* s_pts   = (const float*)d_in[1];
    const float* s_feats = (const float*)d_in[2];
    const int*   inds    = (const int*)d_in[3];
    const float* weights = (const float*)d_in[4];
    const float* kpts    = (const float*)d_in[5];
    float* out = (float*)d_out;

    const int N = in_sizes[0] / 3;               // q_pts is (N,3)
    const int qpb = WAVES * QPW;                 // 8 queries per block
    const int blocks = (N + qpb - 1) / qpb;      // 12500

    const size_t wsNeed = (size_t)N * sizeof(float4);
    if (ws_size >= wsNeed) {
        float4* sp4 = (float4*)d_ws;
        pack_pts<<<(N + 255) / 256, 256, 0, stream>>>(s_pts, sp4, N);
        kpconv_kernel<true><<<blocks, 128, 0, stream>>>(q_pts, s_pts, sp4, s_feats,
                                                        inds, weights, kpts, out, N);
    } else {
        kpconv_kernel<false><<<blocks, 128, 0, stream>>>(q_pts, s_pts, nullptr, s_feats,
                                                         inds, weights, kpts, out, N);
    }
}

// Round 14
// 33.022 us; speedup vs baseline: 1.1592x; 1.1592x over previous
//
#include <hip/hip_runtime.h>

#define H 32
#define C 64
#define K 15
#define SIGMA 0.3f
#define QPW 4            // queries per wave

__global__ __launch_bounds__(64) void kpconv_kernel(
    const float* __restrict__ q_pts,
    const float* __restrict__ s_pts,
    const float* __restrict__ s_feats,
    const int*   __restrict__ inds,
    const float* __restrict__ weights,
    const float* __restrict__ kpts,
    float*       __restrict__ out,
    int N)
{
    // padded row (34 float2 = 272 B): q-rows stay 16B-aligned
    __shared__ float2 list[QPW][34];     // ~1.1 KB, single-wave block

    const int lane = threadIdx.x & 63;
    const int half = lane >> 5;          // query within the pass
    const int hl   = lane & 31;          // neighbor slot

    // wave-uniform kernel points -> SGPRs via s_load
    float kp[K * 3];
    #pragma unroll
    for (int i = 0; i < K * 3; ++i) kp[i] = kpts[i];

    const int qBase = blockIdx.x * QPW;

    int c0 = 0, c1 = 0, c2 = 0, c3 = 0;  // active counts, wave-uniform

    // ---- Phase A: two passes, each pass = 2 queries x 32 neighbors ----
    // (sequential passes: R9 showed fusing these chains costs +1.6us)
    #pragma unroll
    for (int p = 0; p < 2; ++p) {
        const int m = qBase + p * 2 + half;
        float infl = 0.0f;
        int   packed = 0;
        if (m < N) {
            const int idx = inds[m * H + hl];    // coalesced
            if (idx >= 0 && idx < N) {
                const float qx = q_pts[m * 3 + 0];
                const float qy = q_pts[m * 3 + 1];
                const float qz = q_pts[m * 3 + 2];
                const float nx = s_pts[idx * 3 + 0] - qx;
                const float ny = s_pts[idx * 3 + 1] - qy;
                const float nz = s_pts[idx * 3 + 2] - qz;
                float best = 1e30f;
                int   kbest = 0;
                #pragma unroll
                for (int k = 0; k < K; ++k) {    // math bit-identical to R6/R11
                    const float dx = nx - kp[k * 3 + 0];
                    const float dy = ny - kp[k * 3 + 1];
                    const float dz = nz - kp[k * 3 + 2];
                    const float d2 = dx * dx + dy * dy + dz * dz;
                    if (d2 < best) { best = d2; kbest = k; }
                }
                infl = 1.0f - __builtin_amdgcn_sqrtf(best) * (1.0f / SIGMA);
                if (infl < 0.0f) infl = 0.0f;
                packed = idx | (kbest << 20);
            }
        }
        const unsigned long long ball = __ballot(infl > 0.0f);
        const unsigned int lo = (unsigned int)(ball & 0xFFFFFFFFu);
        const unsigned int hi = (unsigned int)(ball >> 32);
        const unsigned int maskH = half ? hi : lo;
        const int rank = __popc(maskH & ((1u << hl) - 1u));
        if (infl > 0.0f)
            list[p * 2 + half][rank] = make_float2(__int_as_float(packed), infl);
        if (p == 0) { c0 = __popc(lo); c1 = __popc(hi); }
        else        { c2 = __popc(lo); c3 = __popc(hi); }
    }
    // same-wave LDS RAW: DS pipe is in-order per wave; no barrier needed.

    // ---- Phase B: quarter-wave per query, float4 channels, 2 pops/iter ----
    const int q  = lane >> 4;            // which of the 4 queries
    const int ql = lane & 15;            // channel group (4 channels)
    const int cq = (q < 2) ? (q == 0 ? c0 : c1) : (q == 2 ? c2 : c3);
    int maxc = c0 > c1 ? c0 : c1;
    if (c2 > maxc) maxc = c2;
    if (c3 > maxc) maxc = c3;

    float4 acc = make_float4(0.0f, 0.0f, 0.0f, 0.0f);
    for (int i = 0; i < maxc; i += 2) {
        if (i < cq) {
            const float4 pf = *(const float4*)&list[q][i];   // 16B aligned
            const int   p0   = __float_as_int(pf.x);
            const float f0   = pf.y;
            const bool  has1 = (i + 1) < cq;
            const int   p1   = has1 ? __float_as_int(pf.z) : 0;   // row 0: hot line
            const float f1   = has1 ? pf.w : 0.0f;
            const float4 a0 = *(const float4*)(s_feats + (size_t)(p0 & 0xFFFFF) * C + ql * 4);
            const float4 w0 = *(const float4*)(weights + (p0 >> 20) * C + ql * 4);
            const float4 a1 = *(const float4*)(s_feats + (size_t)(p1 & 0xFFFFF) * C + ql * 4);
            const float4 w1 = *(const float4*)(weights + (p1 >> 20) * C + ql * 4);
            acc.x += a0.x * w0.x * f0;  acc.y += a0.y * w0.y * f0;
            acc.z += a0.z * w0.z * f0;  acc.w += a0.w * w0.w * f0;
            acc.x += a1.x * w1.x * f1;  acc.y += a1.y * w1.y * f1;
            acc.z += a1.z * w1.z * f1;  acc.w += a1.w * w1.w * f1;
        }
    }

    const int mq = qBase + q;
    if (mq < N)
        *(float4*)(out + (size_t)mq * C + ql * 4) = acc;   // 1KB contiguous per wave
}

extern "C" void kernel_launch(void* const* d_in, const int* in_sizes, int n_in,
                              void* d_out, int out_size, void* d_ws, size_t ws_size,
                              hipStream_t stream) {
    const float* q_pts   = (const float*)d_in[0];
    const float* s_pts   = (const float*)d_in[1];
    const float* s_feats = (const float*)d_in[2];
    const int*   inds    = (const int*)d_in[3];
    const float* weights = (const float*)d_in[4];
    const float* kpts    = (const float*)d_in[5];
    float* out = (float*)d_out;

    const int N = in_sizes[0] / 3;               // q_pts is (N,3)
    const int blocks = (N + QPW - 1) / QPW;      // 25000 single-wave blocks
    kpconv_kernel<<<blocks, 64, 0, stream>>>(q_pts, s_pts, s_feats, inds,
                                             weights, kpts, out, N);
}

// Round 15
// 32.798 us; speedup vs baseline: 1.1671x; 1.0068x over previous
//
#include <hip/hip_runtime.h>

#define H 32
#define C 64
#define K 15
#define SIGMA 0.3f
#define WAVES 2          // waves per block (block = 128): best measured granularity
#define QPW 4            // queries per wave

// Best-known configuration (R11, 32.7 us). Structural sweep complete:
//   block 256/128/64 = 33.4/32.7/33.0; chain fusion +1.6; persistent waves +13;
//   Phase-B unroll +1.0; two-kernel split +9; s_pts float4 pack neutral.
__global__ __launch_bounds__(128) void kpconv_kernel(
    const float* __restrict__ q_pts,
    const float* __restrict__ s_pts,
    const float* __restrict__ s_feats,
    const int*   __restrict__ inds,
    const float* __restrict__ weights,
    const float* __restrict__ kpts,
    float*       __restrict__ out,
    int N)
{
    // padded row (34 float2 = 272 B): q-rows stay 16B-aligned
    __shared__ float2 list[WAVES][QPW][34];   // ~2.2 KB

    const int tid  = threadIdx.x;
    const int wave = tid >> 6;
    const int lane = tid & 63;
    const int half = lane >> 5;          // query within the pass
    const int hl   = lane & 31;          // neighbor slot

    // wave-uniform kernel points -> SGPRs via s_load
    float kp[K * 3];
    #pragma unroll
    for (int i = 0; i < K * 3; ++i) kp[i] = kpts[i];

    const int qBase = (blockIdx.x * WAVES + wave) * QPW;

    int c0 = 0, c1 = 0, c2 = 0, c3 = 0;  // active counts, wave-uniform

    // ---- Phase A: two passes, each pass = 2 queries x 32 neighbors ----
    // (sequential passes: R9 showed fusing these chains costs +1.6us)
    #pragma unroll
    for (int p = 0; p < 2; ++p) {
        const int m = qBase + p * 2 + half;
        float infl = 0.0f;
        int   packed = 0;
        if (m < N) {
            const int idx = inds[m * H + hl];    // coalesced
            if (idx >= 0 && idx < N) {
                const float qx = q_pts[m * 3 + 0];
                const float qy = q_pts[m * 3 + 1];
                const float qz = q_pts[m * 3 + 2];
                const float nx = s_pts[idx * 3 + 0] - qx;
                const float ny = s_pts[idx * 3 + 1] - qy;
                const float nz = s_pts[idx * 3 + 2] - qz;
                float best = 1e30f;
                int   kbest = 0;
                #pragma unroll
                for (int k = 0; k < K; ++k) {    // math bit-identical since R0
                    const float dx = nx - kp[k * 3 + 0];
                    const float dy = ny - kp[k * 3 + 1];
                    const float dz = nz - kp[k * 3 + 2];
                    const float d2 = dx * dx + dy * dy + dz * dz;
                    if (d2 < best) { best = d2; kbest = k; }
                }
                infl = 1.0f - __builtin_amdgcn_sqrtf(best) * (1.0f / SIGMA);
                if (infl < 0.0f) infl = 0.0f;
                packed = idx | (kbest << 20);
            }
        }
        const unsigned long long ball = __ballot(infl > 0.0f);
        const unsigned int lo = (unsigned int)(ball & 0xFFFFFFFFu);
        const unsigned int hi = (unsigned int)(ball >> 32);
        const unsigned int maskH = half ? hi : lo;
        const int rank = __popc(maskH & ((1u << hl) - 1u));
        if (infl > 0.0f)
            list[wave][p * 2 + half][rank] = make_float2(__int_as_float(packed), infl);
        if (p == 0) { c0 = __popc(lo); c1 = __popc(hi); }
        else        { c2 = __popc(lo); c3 = __popc(hi); }
    }
    // same-wave LDS RAW: DS pipe is in-order per wave; no barrier needed.

    // ---- Phase B: quarter-wave per query, float4 channels, 2 pops/iter ----
    const int q  = lane >> 4;            // which of the 4 queries
    const int ql = lane & 15;            // channel group (4 channels)
    const int cq = (q < 2) ? (q == 0 ? c0 : c1) : (q == 2 ? c2 : c3);
    int maxc = c0 > c1 ? c0 : c1;
    if (c2 > maxc) maxc = c2;
    if (c3 > maxc) maxc = c3;

    float4 acc = make_float4(0.0f, 0.0f, 0.0f, 0.0f);
    for (int i = 0; i < maxc; i += 2) {
        if (i < cq) {
            const float4 pf = *(const float4*)&list[wave][q][i];  // 16B aligned
            const int   p0   = __float_as_int(pf.x);
            const float f0   = pf.y;
            const bool  has1 = (i + 1) < cq;
            const int   p1   = has1 ? __float_as_int(pf.z) : 0;   // row 0: hot line
            const float f1   = has1 ? pf.w : 0.0f;
            const float4 a0 = *(const float4*)(s_feats + (size_t)(p0 & 0xFFFFF) * C + ql * 4);
            const float4 w0 = *(const float4*)(weights + (p0 >> 20) * C + ql * 4);
            const float4 a1 = *(const float4*)(s_feats + (size_t)(p1 & 0xFFFFF) * C + ql * 4);
            const float4 w1 = *(const float4*)(weights + (p1 >> 20) * C + ql * 4);
            acc.x += a0.x * w0.x * f0;  acc.y += a0.y * w0.y * f0;
            acc.z += a0.z * w0.z * f0;  acc.w += a0.w * w0.w * f0;
            acc.x += a1.x * w1.x * f1;  acc.y += a1.y * w1.y * f1;
            acc.z += a1.z * w1.z * f1;  acc.w += a1.w * w1.w * f1;
        }
    }

    const int mq = qBase + q;
    if (mq < N)
        *(float4*)(out + (size_t)mq * C + ql * 4) = acc;   // 256B per query
}

extern "C" void kernel_launch(void* const* d_in, const int* in_sizes, int n_in,
                              void* d_out, int out_size, void* d_ws, size_t ws_size,
                              hipStream_t stream) {
    const float* q_pts   = (const float*)d_in[0];
    const float* s_pts   = (const float*)d_in[1];
    const float* s_feats = (const float*)d_in[2];
    const int*   inds    = (const int*)d_in[3];
    const float* weights = (const float*)d_in[4];
    const float* kpts    = (const float*)d_in[5];
    float* out = (float*)d_out;

    const int N = in_sizes[0] / 3;               // q_pts is (N,3)
    const int qpb = WAVES * QPW;                 // 8 queries per block
    const int blocks = (N + qpb - 1) / qpb;      // 12500
    kpconv_kernel<<<blocks, 128, 0, stream>>>(q_pts, s_pts, s_feats, inds,
                                              weights, kpts, out, N);
}